// Round 5
// baseline (54.519 us; speedup 1.0000x reference)
//
#include <hip/hip_runtime.h>
#include <hip/hip_bf16.h>

typedef __attribute__((ext_vector_type(8))) short bf16x8;
typedef __attribute__((ext_vector_type(4))) float f32x4;
typedef unsigned short u16;
typedef unsigned int u32;

__device__ __forceinline__ float sigm(float x) { return 1.f / (1.f + __expf(-x)); }
__device__ __forceinline__ float red16(float x) {
    x += __shfl_xor(x, 1, 64);
    x += __shfl_xor(x, 2, 64);
    x += __shfl_xor(x, 4, 64);
    x += __shfl_xor(x, 8, 64);
    return x;
}
// fp32x8 -> bf16x8 via compiler casts (lowers to v_cvt_pk_bf16_f32 pairs)
__device__ __forceinline__ bf16x8 cvt8(const float* s) {
    f32x4 v0 = *(const f32x4*)s;
    f32x4 v1 = *(const f32x4*)(s + 4);
    bf16x8 t;
    t[0] = (short)__builtin_bit_cast(u16, __float2bfloat16(v0.x));
    t[1] = (short)__builtin_bit_cast(u16, __float2bfloat16(v0.y));
    t[2] = (short)__builtin_bit_cast(u16, __float2bfloat16(v0.z));
    t[3] = (short)__builtin_bit_cast(u16, __float2bfloat16(v0.w));
    t[4] = (short)__builtin_bit_cast(u16, __float2bfloat16(v1.x));
    t[5] = (short)__builtin_bit_cast(u16, __float2bfloat16(v1.y));
    t[6] = (short)__builtin_bit_cast(u16, __float2bfloat16(v1.z));
    t[7] = (short)__builtin_bit_cast(u16, __float2bfloat16(v1.w));
    return t;
}

// ---- single fused kernel: paired GEMM + LN + ReLU + interaction -------------
// 384 blocks = (pair:3, mtile:128). 512 thr = 8 waves; wave owns N cols
// [wave*32, wave*32+32) for BOTH gemms (g=0:G, g=1:P) -> interaction combine is
// lane-local (no inter-wave exchange). W is fp32, converted to bf16 fragments
// in-register inside the loop (kills the prep kernel + launch gap).
struct PairTask {
    const float *xG, *xP;                   // fp32 inputs [2048][256]
    const float *WG, *WP;                   // fp32 weights [256][256] (row=n, col=k)
    const float *bG, *gmG, *beG;
    const float *bP, *gmP, *beP;
    const float *awG, *awP;                 // awG=apw (dots oG), awP=agw (dots oP)
    const float *attbP, *attbG;             // apb, agb
    float *outG, *outP;
    int interact;
};
struct FusedArgs { PairTask p[3]; };

__global__ __launch_bounds__(512) void fused_kernel(FusedArgs args) {
    __shared__ float red_s[2][16][8];
    __shared__ float red_q[2][16][8];
    __shared__ float red_d[2][16][8];

    int wg = blockIdx.x;
    int swz = (wg & 7) * 48 + (wg >> 3);    // XCD swizzle, 384 % 8 == 0, bijective
    int pair = swz >> 7;
    int mt = swz & 127;
    PairTask tk = args.p[pair];

    int tid = threadIdx.x;
    int wave = tid >> 6;
    int lane = tid & 63;
    int cq = lane & 15, rq = lane >> 4;

    // ---- A fragments: both gemms' 16 rows, fp32 load + convert in-register --
    const float* xg = tk.xG + (size_t)(mt * 16 + cq) * 256 + rq * 8;
    const float* xp = tk.xP + (size_t)(mt * 16 + cq) * 256 + rq * 8;
    bf16x8 aF[2][8];
#pragma unroll
    for (int kk = 0; kk < 8; ++kk) {
        aF[0][kk] = cvt8(xg + kk * 32);
        aF[1][kk] = cvt8(xp + kk * 32);
    }

    f32x4 acc[2][2];
#pragma unroll
    for (int g = 0; g < 2; ++g)
#pragma unroll
        for (int nt = 0; nt < 2; ++nt) acc[g][nt] = (f32x4){0.f, 0.f, 0.f, 0.f};

    // B-frag source rows: n = wave*32 + nt*16 + cq, k = kk*32 + rq*8 (+e)
    const float* wg0 = tk.WG + (size_t)(wave * 32 + cq) * 256 + rq * 8;
    const float* wp0 = tk.WP + (size_t)(wave * 32 + cq) * 256 + rq * 8;

    // ---- main loop: 32 fp32 loads + converts + 32 MFMAs, no barriers --------
#pragma unroll
    for (int kk = 0; kk < 8; ++kk) {
#pragma unroll
        for (int nt = 0; nt < 2; ++nt) {
            bf16x8 b0 = cvt8(wg0 + (size_t)nt * 16 * 256 + kk * 32);
            acc[0][nt] = __builtin_amdgcn_mfma_f32_16x16x32_bf16(aF[0][kk], b0, acc[0][nt], 0, 0, 0);
            bf16x8 b1 = cvt8(wp0 + (size_t)nt * 16 * 256 + kk * 32);
            acc[1][nt] = __builtin_amdgcn_mfma_f32_16x16x32_bf16(aF[1][kk], b1, acc[1][nt], 0, 0, 0);
        }
    }

    // ---------------------------- epilogue -----------------------------------
    float bb[2][2], gm[2][2], be[2][2], aw[2][2];
#pragma unroll
    for (int g = 0; g < 2; ++g)
#pragma unroll
        for (int nt = 0; nt < 2; ++nt) {
            int c = wave * 32 + nt * 16 + cq;
            bb[g][nt] = g ? tk.bP[c] : tk.bG[c];
            gm[g][nt] = g ? tk.gmP[c] : tk.gmG[c];
            be[g][nt] = g ? tk.beP[c] : tk.beG[c];
            aw[g][nt] = tk.interact ? (g ? tk.awP[c] : tk.awG[c]) : 0.f;
        }

    // bias add in place; row stats (sum over the 256 N-cols per row)
#pragma unroll
    for (int r = 0; r < 4; ++r) {
#pragma unroll
        for (int g = 0; g < 2; ++g) {
            float s = 0.f, q = 0.f;
#pragma unroll
            for (int nt = 0; nt < 2; ++nt) {
                float t = acc[g][nt][r] + bb[g][nt];
                acc[g][nt][r] = t;
                s += t; q += t * t;
            }
            s = red16(s); q = red16(q);
            if (cq == 0) {
                red_s[g][rq * 4 + r][wave] = s;
                red_q[g][rq * 4 + r][wave] = q;
            }
        }
    }
    __syncthreads();

    // LN + ReLU in place (acc becomes o)
#pragma unroll
    for (int r = 0; r < 4; ++r) {
        int row = rq * 4 + r;
#pragma unroll
        for (int g = 0; g < 2; ++g) {
            f32x4 s4 = *(const f32x4*)&red_s[g][row][0];
            f32x4 s5 = *(const f32x4*)&red_s[g][row][4];
            f32x4 q4 = *(const f32x4*)&red_q[g][row][0];
            f32x4 q5 = *(const f32x4*)&red_q[g][row][4];
            float s = s4.x + s4.y + s4.z + s4.w + s5.x + s5.y + s5.z + s5.w;
            float q = q4.x + q4.y + q4.z + q4.w + q5.x + q5.y + q5.z + q5.w;
            float mean = s * (1.f / 256.f);
            float var = q * (1.f / 256.f) - mean * mean;
            float rstd = rsqrtf(var + 1e-5f);
#pragma unroll
            for (int nt = 0; nt < 2; ++nt)
                acc[g][nt][r] = fmaxf((acc[g][nt][r] - mean) * rstd * gm[g][nt] + be[g][nt], 0.f);
        }
    }

    if (!tk.interact) {
#pragma unroll
        for (int r = 0; r < 4; ++r) {
            int grow = mt * 16 + rq * 4 + r;
#pragma unroll
            for (int nt = 0; nt < 2; ++nt) {
                int c = wave * 32 + nt * 16 + cq;
                tk.outG[(size_t)grow * 256 + c] = acc[0][nt][r];
                tk.outP[(size_t)grow * 256 + c] = acc[1][nt][r];
            }
        }
    } else {
        // per-row attention dots
#pragma unroll
        for (int r = 0; r < 4; ++r) {
#pragma unroll
            for (int g = 0; g < 2; ++g) {
                float pd = 0.f;
#pragma unroll
                for (int nt = 0; nt < 2; ++nt) pd += acc[g][nt][r] * aw[g][nt];
                pd = red16(pd);
                if (cq == 0) red_d[g][rq * 4 + r][wave] = pd;
            }
        }
        __syncthreads();
        float battP = *tk.attbP, battG = *tk.attbG;
#pragma unroll
        for (int r = 0; r < 4; ++r) {
            int row = rq * 4 + r;
            f32x4 d4 = *(const f32x4*)&red_d[0][row][0];
            f32x4 d5 = *(const f32x4*)&red_d[0][row][4];
            f32x4 e4 = *(const f32x4*)&red_d[1][row][0];
            f32x4 e5 = *(const f32x4*)&red_d[1][row][4];
            float dG = d4.x + d4.y + d4.z + d4.w + d5.x + d5.y + d5.z + d5.w;  // dot(g_align, apw)
            float dP = e4.x + e4.y + e4.z + e4.w + e5.x + e5.y + e5.z + e5.w;  // dot(p_align, agw)
            int grow = mt * 16 + row;
#pragma unroll
            for (int nt = 0; nt < 2; ++nt) {
                int c = wave * 32 + nt * 16 + cq;
                float og = acc[0][nt][r], op = acc[1][nt][r];
                tk.outG[(size_t)grow * 256 + c] =
                    op * sigm(op * dG + battP) + og * sigm(og * dP + battG);
            }
        }
    }
}

// -----------------------------------------------------------------------------
extern "C" void kernel_launch(void* const* d_in, const int* in_sizes, int n_in,
                              void* d_out, int out_size, void* d_ws, size_t ws_size,
                              hipStream_t stream) {
    const float* gfeat = (const float*)d_in[0];
    const float* pfeat = (const float*)d_in[1];
    float* out = (float*)d_out;
    const size_t S = (size_t)2048 * 256;

    float* out_common = out + 0 * S;
    float* out_syn    = out + 1 * S;
    float* out_gspec  = out + 2 * S;
    float* out_pspec  = out + 3 * S;

    FusedArgs fa;
    // pair 0: spec — G: mlp(gfeat, gs_*) -> g_spec ; P: mlp(pfeat, ps_*) -> p_spec
    fa.p[0] = { gfeat, pfeat,
                (const float*)d_in[2], (const float*)d_in[6],
                (const float*)d_in[3], (const float*)d_in[4], (const float*)d_in[5],
                (const float*)d_in[7], (const float*)d_in[8], (const float*)d_in[9],
                nullptr, nullptr, nullptr, nullptr,
                out_gspec, out_pspec, 0 };
    // pair 1: common — G: mlp(pfeat, c_g_*), P: mlp(gfeat, c_p_*)
    fa.p[1] = { pfeat, gfeat,
                (const float*)d_in[10], (const float*)d_in[14],
                (const float*)d_in[11], (const float*)d_in[12], (const float*)d_in[13],
                (const float*)d_in[15], (const float*)d_in[16], (const float*)d_in[17],
                (const float*)d_in[20] /*c_apw*/, (const float*)d_in[18] /*c_agw*/,
                (const float*)d_in[21] /*c_apb*/, (const float*)d_in[19] /*c_agb*/,
                out_common, nullptr, 1 };
    // pair 2: synergy — G: mlp(pfeat, s_g_*), P: mlp(gfeat, s_p_*)
    fa.p[2] = { pfeat, gfeat,
                (const float*)d_in[22], (const float*)d_in[26],
                (const float*)d_in[23], (const float*)d_in[24], (const float*)d_in[25],
                (const float*)d_in[27], (const float*)d_in[28], (const float*)d_in[29],
                (const float*)d_in[32] /*s_apw*/, (const float*)d_in[30] /*s_agw*/,
                (const float*)d_in[33] /*s_apb*/, (const float*)d_in[31] /*s_agb*/,
                out_syn, nullptr, 1 };

    hipLaunchKernelGGL(fused_kernel, dim3(384), dim3(512), 0, stream, fa);
}

// Round 6
// 27.127 us; speedup vs baseline: 2.0098x; 2.0098x over previous
//
#include <hip/hip_runtime.h>
#include <hip/hip_bf16.h>

typedef __attribute__((ext_vector_type(8))) short bf16x8;
typedef __attribute__((ext_vector_type(4))) float f32x4;
typedef unsigned short u16;
typedef unsigned int u32;

__device__ __forceinline__ u16 f2bf(float f) {
    u32 u = __builtin_bit_cast(u32, f);
    return (u16)((u + 0x7FFFu + ((u >> 16) & 1u)) >> 16);
}
__device__ __forceinline__ float sigm(float x) { return 1.f / (1.f + __expf(-x)); }
__device__ __forceinline__ float red16(float x) {
    x += __shfl_xor(x, 1, 64);
    x += __shfl_xor(x, 2, 64);
    x += __shfl_xor(x, 4, 64);
    x += __shfl_xor(x, 8, 64);
    return x;
}
__device__ __forceinline__ uint4 pack8(const float* s) {
    f32x4 v0 = *(const f32x4*)s;
    f32x4 v1 = *(const f32x4*)(s + 4);
    uint4 o;
    o.x = (u32)f2bf(v0.x) | ((u32)f2bf(v0.y) << 16);
    o.y = (u32)f2bf(v0.z) | ((u32)f2bf(v0.w) << 16);
    o.z = (u32)f2bf(v1.x) | ((u32)f2bf(v1.y) << 16);
    o.w = (u32)f2bf(v1.z) | ((u32)f2bf(v1.w) << 16);
    return o;
}
__device__ __forceinline__ void gload_lds16(const void* g, void* l) {
    __builtin_amdgcn_global_load_lds((const __attribute__((address_space(1))) u32*)g,
                                     (__attribute__((address_space(3))) u32*)l, 16, 0, 0);
}

// ---------------- prep v2: coalesced READ, scattered frag WRITE --------------
// wf layout: [mlp6][cg:16][kk:8][lane:64][e:8]  (65536 u16 per mlp)
//   n = cg*16 + (lane&15), k = kk*32 + (lane>>4)*8 + e
// xf layout: [tensor2][mt:128][kk:8][lane:64][e:8] (524288 u16 per tensor)
struct PrepArgs { const float* W[6]; const float* xg; const float* xp; u16* wf; u16* xf; };

__global__ __launch_bounds__(256) void prep_kernel(PrepArgs a) {
    int t = blockIdx.x * 256 + threadIdx.x;       // 180224 threads, 8 fp32 each
    if (t < 49152) {                              // W part: contiguous source read
        int mlp = t >> 13, r = t & 8191;          // r = uint4 index inside W[mlp]
        const float* s = a.W[mlp] + (size_t)r * 8;
        int n = r >> 5, kq = r & 31;              // k0 = kq*8
        int kk = kq >> 2, lhi = kq & 3;
        int lane = lhi * 16 + (n & 15);
        int dst = ((mlp * 16 + (n >> 4)) * 8 + kk) * 64 + lane;
        *(uint4*)(a.wf + (size_t)dst * 8) = pack8(s);
    } else {                                      // x part
        int u = t - 49152;                        // < 131072
        int tt = u >> 16, r = u & 65535;
        const float* s = (tt ? a.xp : a.xg) + (size_t)r * 8;
        int row = r >> 5, kq = r & 31;
        int kk = kq >> 2, lhi = kq & 3;
        int lane = lhi * 16 + (row & 15);
        int dst = ((tt * 128 + (row >> 4)) * 8 + kk) * 64 + lane;
        *(uint4*)(a.xf + (size_t)dst * 8) = pack8(s);
    }
}

// ---------------- fused: paired GEMM + LN + ReLU + interaction ---------------
// 192 blocks = (pair:3, mchunk:64 of 32 rows). 512 thr = 8 waves; wave owns
// cols [wave*32, wave*32+32) for BOTH gemms (lane-local interaction combine).
// A (both gemms, 32 rows) staged once into LDS; each B frag reused for 2 mtiles.
struct PairTask {
    const u16 *xfG, *xfP;                   // A-frag tensors [128][8][64][8]
    const u16 *WG, *WP;                     // B-frag tensors [16][8][64][8]
    const float *bG, *gmG, *beG;
    const float *bP, *gmP, *beP;
    const float *awG, *awP;                 // awG=apw (dots oG), awP=agw (dots oP)
    const float *attbP, *attbG;             // apb, agb
    float *outG, *outP;
    int interact;
};
struct FusedArgs { PairTask p[3]; };

__global__ __launch_bounds__(512) void fused_kernel(FusedArgs args) {
    __shared__ u16 A_lds[4 * 8 * 64 * 8];   // [c=(g,m)][kk][lane][8] = 32 KB
    __shared__ float red_s[2][32][8];
    __shared__ float red_q[2][32][8];
    __shared__ float red_d[2][32][8];

    int wg = blockIdx.x;
    int swz = (wg & 7) * 24 + (wg >> 3);    // XCD swizzle, 192 % 8 == 0, bijective
    int pair = swz >> 6;
    int mc = swz & 63;                      // 32-row chunk
    PairTask tk = args.p[pair];

    int tid = threadIdx.x;
    int wave = tid >> 6;
    int lane = tid & 63;
    int cq = lane & 15, rq = lane >> 4;

    // ---- stage A: 4 chunks (g,m) x 8KB, coalesced global_load_lds ----------
    const u16* xsrc0 = tk.xfG;
    const u16* xsrc1 = tk.xfP;
#pragma unroll
    for (int c = 0; c < 4; ++c) {
        const u16* base = (c >> 1) ? xsrc1 : xsrc0;
        const u16* src = base + (size_t)(mc * 2 + (c & 1)) * 4096 + tid * 8;
        gload_lds16(src, (char*)A_lds + c * 8192 + wave * 1024);
    }
    __syncthreads();                        // drains vmcnt before barrier

    f32x4 acc[2][2][2];                     // [g][m][nt]
#pragma unroll
    for (int g = 0; g < 2; ++g)
#pragma unroll
        for (int m = 0; m < 2; ++m)
#pragma unroll
            for (int nt = 0; nt < 2; ++nt) acc[g][m][nt] = (f32x4){0.f, 0.f, 0.f, 0.f};

    const u16* wb0 = tk.WG + ((size_t)(wave * 2) * 8) * 512 + lane * 8;
    const u16* wb1 = tk.WP + ((size_t)(wave * 2) * 8) * 512 + lane * 8;

    // ---- main loop: per kk: 4 coalesced B loads + 4 ds_reads + 8 MFMAs -----
#pragma unroll
    for (int kk = 0; kk < 8; ++kk) {
#pragma unroll
        for (int g = 0; g < 2; ++g) {
            bf16x8 a0 = *(const bf16x8*)&A_lds[((g * 2 + 0) * 8 + kk) * 512 + lane * 8];
            bf16x8 a1 = *(const bf16x8*)&A_lds[((g * 2 + 1) * 8 + kk) * 512 + lane * 8];
            const u16* wb = g ? wb1 : wb0;
#pragma unroll
            for (int nt = 0; nt < 2; ++nt) {
                bf16x8 b = *(const bf16x8*)(wb + (size_t)(nt * 8 + kk) * 512);
                acc[g][0][nt] = __builtin_amdgcn_mfma_f32_16x16x32_bf16(a0, b, acc[g][0][nt], 0, 0, 0);
                acc[g][1][nt] = __builtin_amdgcn_mfma_f32_16x16x32_bf16(a1, b, acc[g][1][nt], 0, 0, 0);
            }
        }
    }

    // ---------------------------- epilogue ----------------------------------
    float bb[2][2], gm[2][2], be[2][2], aw[2][2];
#pragma unroll
    for (int g = 0; g < 2; ++g)
#pragma unroll
        for (int nt = 0; nt < 2; ++nt) {
            int c = wave * 32 + nt * 16 + cq;
            bb[g][nt] = g ? tk.bP[c] : tk.bG[c];
            gm[g][nt] = g ? tk.gmP[c] : tk.gmG[c];
            be[g][nt] = g ? tk.beP[c] : tk.beG[c];
            aw[g][nt] = tk.interact ? (g ? tk.awP[c] : tk.awG[c]) : 0.f;
        }

    // bias add in place; per-row stats
#pragma unroll
    for (int m = 0; m < 2; ++m)
#pragma unroll
        for (int r = 0; r < 4; ++r) {
#pragma unroll
            for (int g = 0; g < 2; ++g) {
                float s = 0.f, q = 0.f;
#pragma unroll
                for (int nt = 0; nt < 2; ++nt) {
                    float t = acc[g][m][nt][r] + bb[g][nt];
                    acc[g][m][nt][r] = t;
                    s += t; q += t * t;
                }
                s = red16(s); q = red16(q);
                if (cq == 0) {
                    red_s[g][m * 16 + rq * 4 + r][wave] = s;
                    red_q[g][m * 16 + rq * 4 + r][wave] = q;
                }
            }
        }
    __syncthreads();

    // LN + ReLU in place (acc becomes o)
#pragma unroll
    for (int m = 0; m < 2; ++m)
#pragma unroll
        for (int r = 0; r < 4; ++r) {
            int row = m * 16 + rq * 4 + r;
#pragma unroll
            for (int g = 0; g < 2; ++g) {
                f32x4 s4 = *(const f32x4*)&red_s[g][row][0];
                f32x4 s5 = *(const f32x4*)&red_s[g][row][4];
                f32x4 q4 = *(const f32x4*)&red_q[g][row][0];
                f32x4 q5 = *(const f32x4*)&red_q[g][row][4];
                float s = s4.x + s4.y + s4.z + s4.w + s5.x + s5.y + s5.z + s5.w;
                float q = q4.x + q4.y + q4.z + q4.w + q5.x + q5.y + q5.z + q5.w;
                float mean = s * (1.f / 256.f);
                float var = q * (1.f / 256.f) - mean * mean;
                float rstd = rsqrtf(var + 1e-5f);
#pragma unroll
                for (int nt = 0; nt < 2; ++nt)
                    acc[g][m][nt][r] = fmaxf((acc[g][m][nt][r] - mean) * rstd * gm[g][nt] + be[g][nt], 0.f);
            }
        }

    if (!tk.interact) {
#pragma unroll
        for (int m = 0; m < 2; ++m)
#pragma unroll
            for (int r = 0; r < 4; ++r) {
                int grow = mc * 32 + m * 16 + rq * 4 + r;
#pragma unroll
                for (int nt = 0; nt < 2; ++nt) {
                    int c = wave * 32 + nt * 16 + cq;
                    tk.outG[(size_t)grow * 256 + c] = acc[0][m][nt][r];
                    tk.outP[(size_t)grow * 256 + c] = acc[1][m][nt][r];
                }
            }
    } else {
        // per-row attention dots
#pragma unroll
        for (int m = 0; m < 2; ++m)
#pragma unroll
            for (int r = 0; r < 4; ++r) {
#pragma unroll
                for (int g = 0; g < 2; ++g) {
                    float pd = 0.f;
#pragma unroll
                    for (int nt = 0; nt < 2; ++nt) pd += acc[g][m][nt][r] * aw[g][nt];
                    pd = red16(pd);
                    if (cq == 0) red_d[g][m * 16 + rq * 4 + r][wave] = pd;
                }
            }
        __syncthreads();
        float battP = *tk.attbP, battG = *tk.attbG;
#pragma unroll
        for (int m = 0; m < 2; ++m)
#pragma unroll
            for (int r = 0; r < 4; ++r) {
                int row = m * 16 + rq * 4 + r;
                f32x4 d4 = *(const f32x4*)&red_d[0][row][0];
                f32x4 d5 = *(const f32x4*)&red_d[0][row][4];
                f32x4 e4 = *(const f32x4*)&red_d[1][row][0];
                f32x4 e5 = *(const f32x4*)&red_d[1][row][4];
                float dG = d4.x + d4.y + d4.z + d4.w + d5.x + d5.y + d5.z + d5.w;  // dot(g_align, apw)
                float dP = e4.x + e4.y + e4.z + e4.w + e5.x + e5.y + e5.z + e5.w;  // dot(p_align, agw)
                int grow = mc * 32 + row;
#pragma unroll
                for (int nt = 0; nt < 2; ++nt) {
                    int c = wave * 32 + nt * 16 + cq;
                    float og = acc[0][m][nt][r], op = acc[1][m][nt][r];
                    tk.outG[(size_t)grow * 256 + c] =
                        op * sigm(op * dG + battP) + og * sigm(og * dP + battG);
                }
            }
    }
}

// -----------------------------------------------------------------------------
extern "C" void kernel_launch(void* const* d_in, const int* in_sizes, int n_in,
                              void* d_out, int out_size, void* d_ws, size_t ws_size,
                              hipStream_t stream) {
    const float* gfeat = (const float*)d_in[0];
    const float* pfeat = (const float*)d_in[1];
    float* out = (float*)d_out;
    const size_t S = (size_t)2048 * 256;

    float* out_common = out + 0 * S;
    float* out_syn    = out + 1 * S;
    float* out_gspec  = out + 2 * S;
    float* out_pspec  = out + 3 * S;

    u16* wf = (u16*)d_ws;                   // 6 * 65536 u16
    u16* xf = wf + 6 * 65536;               // 2 * 524288 u16
    u16* xf_g = xf;
    u16* xf_p = xf + 524288;

    PrepArgs pa;
    pa.W[0] = (const float*)d_in[2];    // gs_W
    pa.W[1] = (const float*)d_in[6];    // ps_W
    pa.W[2] = (const float*)d_in[10];   // c_g_W
    pa.W[3] = (const float*)d_in[14];   // c_p_W
    pa.W[4] = (const float*)d_in[22];   // s_g_W
    pa.W[5] = (const float*)d_in[26];   // s_p_W
    pa.xg = gfeat; pa.xp = pfeat;
    pa.wf = wf; pa.xf = xf;
    hipLaunchKernelGGL(prep_kernel, dim3(704), dim3(256), 0, stream, pa);

    FusedArgs fa;
    // pair 0: spec — G: mlp(gfeat, gs_*) -> g_spec ; P: mlp(pfeat, ps_*) -> p_spec
    fa.p[0] = { xf_g, xf_p, wf + 0 * 65536, wf + 1 * 65536,
                (const float*)d_in[3], (const float*)d_in[4], (const float*)d_in[5],
                (const float*)d_in[7], (const float*)d_in[8], (const float*)d_in[9],
                nullptr, nullptr, nullptr, nullptr,
                out_gspec, out_pspec, 0 };
    // pair 1: common — G: mlp(pfeat, c_g_*), P: mlp(gfeat, c_p_*)
    fa.p[1] = { xf_p, xf_g, wf + 2 * 65536, wf + 3 * 65536,
                (const float*)d_in[11], (const float*)d_in[12], (const float*)d_in[13],
                (const float*)d_in[15], (const float*)d_in[16], (const float*)d_in[17],
                (const float*)d_in[20] /*c_apw*/, (const float*)d_in[18] /*c_agw*/,
                (const float*)d_in[21] /*c_apb*/, (const float*)d_in[19] /*c_agb*/,
                out_common, nullptr, 1 };
    // pair 2: synergy — G: mlp(pfeat, s_g_*), P: mlp(gfeat, s_p_*)
    fa.p[2] = { xf_p, xf_g, wf + 4 * 65536, wf + 5 * 65536,
                (const float*)d_in[23], (const float*)d_in[24], (const float*)d_in[25],
                (const float*)d_in[27], (const float*)d_in[28], (const float*)d_in[29],
                (const float*)d_in[32] /*s_apw*/, (const float*)d_in[30] /*s_agw*/,
                (const float*)d_in[33] /*s_apb*/, (const float*)d_in[31] /*s_agb*/,
                out_syn, nullptr, 1 };

    hipLaunchKernelGGL(fused_kernel, dim3(192), dim3(512), 0, stream, fa);
}

// Round 7
// 26.684 us; speedup vs baseline: 2.0431x; 1.0166x over previous
//
#include <hip/hip_runtime.h>
#include <hip/hip_bf16.h>

typedef __attribute__((ext_vector_type(8))) short bf16x8;
typedef __attribute__((ext_vector_type(4))) float f32x4;
typedef unsigned short u16;
typedef unsigned int u32;

__device__ __forceinline__ u16 f2bf(float f) {
    u32 u = __builtin_bit_cast(u32, f);
    return (u16)((u + 0x7FFFu + ((u >> 16) & 1u)) >> 16);
}
__device__ __forceinline__ float sigm(float x) { return 1.f / (1.f + __expf(-x)); }
__device__ __forceinline__ float red16(float x) {
    x += __shfl_xor(x, 1, 64);
    x += __shfl_xor(x, 2, 64);
    x += __shfl_xor(x, 4, 64);
    x += __shfl_xor(x, 8, 64);
    return x;
}
__device__ __forceinline__ uint4 pack8(const float* s) {
    f32x4 v0 = *(const f32x4*)s;
    f32x4 v1 = *(const f32x4*)(s + 4);
    uint4 o;
    o.x = (u32)f2bf(v0.x) | ((u32)f2bf(v0.y) << 16);
    o.y = (u32)f2bf(v0.z) | ((u32)f2bf(v0.w) << 16);
    o.z = (u32)f2bf(v1.x) | ((u32)f2bf(v1.y) << 16);
    o.w = (u32)f2bf(v1.z) | ((u32)f2bf(v1.w) << 16);
    return o;
}

// ---------------- prep: coalesced READ, fragment-order WRITE -----------------
// wf layout: [mlp6][c:16][kk:8][lane:64][e:8]  (65536 u16 per mlp)
//   n = c*16 + (lane&15), k = kk*32 + (lane>>4)*8 + e
// xf layout: [tensor2][mt:128][kk:8][lane:64][e:8] (524288 u16 per tensor)
struct PrepArgs { const float* W[6]; const float* xg; const float* xp; u16* wf; u16* xf; };

__global__ __launch_bounds__(256) void prep_kernel(PrepArgs a) {
    int t = blockIdx.x * 256 + threadIdx.x;       // 180224 threads, 8 fp32 each
    if (t < 49152) {                              // W part: contiguous source read
        int mlp = t >> 13, r = t & 8191;          // r = uint4 index inside W[mlp]
        const float* s = a.W[mlp] + (size_t)r * 8;
        int n = r >> 5, kq = r & 31;              // k0 = kq*8
        int kk = kq >> 2, lhi = kq & 3;
        int lane = lhi * 16 + (n & 15);
        int dst = ((mlp * 16 + (n >> 4)) * 8 + kk) * 64 + lane;
        *(uint4*)(a.wf + (size_t)dst * 8) = pack8(s);
    } else {                                      // x part
        int u = t - 49152;                        // < 131072
        int tt = u >> 16, r = u & 65535;
        const float* s = (tt ? a.xp : a.xg) + (size_t)r * 8;
        int row = r >> 5, kq = r & 31;
        int kk = kq >> 2, lhi = kq & 3;
        int lane = lhi * 16 + (row & 15);
        int dst = ((tt * 128 + (row >> 4)) * 8 + kk) * 64 + lane;
        *(uint4*)(a.xf + (size_t)dst * 8) = pack8(s);
    }
}

// ---------------- fused: paired GEMM + LN + ReLU + interaction ---------------
// 384 blocks = (pair:3, mt:128 of 16 rows). 512 thr = 8 waves; wave owns cols
// [wave*32, wave*32+32) for BOTH gemms (lane-local interaction). No LDS / no
// barriers in the main loop; 48 independent coalesced loads stream from L2.
struct PairTask {
    const u16 *xfG, *xfP;                   // A-frag tensors [128][8][64][8]
    const u16 *WG, *WP;                     // B-frag tensors [16][8][64][8]
    const float *bG, *gmG, *beG;
    const float *bP, *gmP, *beP;
    const float *awG, *awP;                 // awG=apw (dots oG), awP=agw (dots oP)
    const float *attbP, *attbG;             // apb, agb
    float *outG, *outP;
    int interact;
};
struct FusedArgs { PairTask p[3]; };

__global__ __launch_bounds__(512, 2) void fused_kernel(FusedArgs args) {
    __shared__ float red_s[2][16][8];
    __shared__ float red_q[2][16][8];
    __shared__ float red_d[2][16][8];

    int wg = blockIdx.x;
    int swz = (wg & 7) * 48 + (wg >> 3);    // XCD swizzle, 384 % 8 == 0, bijective
    int pair = swz >> 7;
    int mt = swz & 127;
    PairTask tk = args.p[pair];

    int tid = threadIdx.x;
    int wave = tid >> 6;
    int lane = tid & 63;
    int cq = lane & 15, rq = lane >> 4;

    f32x4 acc[2][2];
#pragma unroll
    for (int g = 0; g < 2; ++g)
#pragma unroll
        for (int nt = 0; nt < 2; ++nt) acc[g][nt] = (f32x4){0.f, 0.f, 0.f, 0.f};

    // frag bases (u16 units). B: c = wave*2 + nt -> off = wave*8192 + nt*4096 + kk*512
    const u16* xaG = tk.xfG + (size_t)mt * 4096 + lane * 8;
    const u16* xaP = tk.xfP + (size_t)mt * 4096 + lane * 8;
    const u16* wbG = tk.WG + (size_t)wave * 8192 + lane * 8;
    const u16* wbP = tk.WP + (size_t)wave * 8192 + lane * 8;

    // ---- main loop: 8 kk x {2 A loads + 4 B loads + 4 MFMAs}, no barriers ---
#pragma unroll
    for (int kk = 0; kk < 8; ++kk) {
        bf16x8 aG  = *(const bf16x8*)(xaG + kk * 512);
        bf16x8 aP  = *(const bf16x8*)(xaP + kk * 512);
        bf16x8 bG0 = *(const bf16x8*)(wbG + kk * 512);
        bf16x8 bG1 = *(const bf16x8*)(wbG + 4096 + kk * 512);
        bf16x8 bP0 = *(const bf16x8*)(wbP + kk * 512);
        bf16x8 bP1 = *(const bf16x8*)(wbP + 4096 + kk * 512);
        acc[0][0] = __builtin_amdgcn_mfma_f32_16x16x32_bf16(aG, bG0, acc[0][0], 0, 0, 0);
        acc[0][1] = __builtin_amdgcn_mfma_f32_16x16x32_bf16(aG, bG1, acc[0][1], 0, 0, 0);
        acc[1][0] = __builtin_amdgcn_mfma_f32_16x16x32_bf16(aP, bP0, acc[1][0], 0, 0, 0);
        acc[1][1] = __builtin_amdgcn_mfma_f32_16x16x32_bf16(aP, bP1, acc[1][1], 0, 0, 0);
    }

    // ---------------------------- epilogue -----------------------------------
    float bb[2][2], gm[2][2], be[2][2], aw[2][2];
#pragma unroll
    for (int g = 0; g < 2; ++g)
#pragma unroll
        for (int nt = 0; nt < 2; ++nt) {
            int c = wave * 32 + nt * 16 + cq;
            bb[g][nt] = g ? tk.bP[c] : tk.bG[c];
            gm[g][nt] = g ? tk.gmP[c] : tk.gmG[c];
            be[g][nt] = g ? tk.beP[c] : tk.beG[c];
            aw[g][nt] = tk.interact ? (g ? tk.awP[c] : tk.awG[c]) : 0.f;
        }

    // bias add in place; row stats (sum over the 256 N-cols per row)
#pragma unroll
    for (int r = 0; r < 4; ++r) {
#pragma unroll
        for (int g = 0; g < 2; ++g) {
            float s = 0.f, q = 0.f;
#pragma unroll
            for (int nt = 0; nt < 2; ++nt) {
                float t = acc[g][nt][r] + bb[g][nt];
                acc[g][nt][r] = t;
                s += t; q += t * t;
            }
            s = red16(s); q = red16(q);
            if (cq == 0) {
                red_s[g][rq * 4 + r][wave] = s;
                red_q[g][rq * 4 + r][wave] = q;
            }
        }
    }
    __syncthreads();

    // LN + ReLU in place (acc becomes o)
#pragma unroll
    for (int r = 0; r < 4; ++r) {
        int row = rq * 4 + r;
#pragma unroll
        for (int g = 0; g < 2; ++g) {
            f32x4 s4 = *(const f32x4*)&red_s[g][row][0];
            f32x4 s5 = *(const f32x4*)&red_s[g][row][4];
            f32x4 q4 = *(const f32x4*)&red_q[g][row][0];
            f32x4 q5 = *(const f32x4*)&red_q[g][row][4];
            float s = s4.x + s4.y + s4.z + s4.w + s5.x + s5.y + s5.z + s5.w;
            float q = q4.x + q4.y + q4.z + q4.w + q5.x + q5.y + q5.z + q5.w;
            float mean = s * (1.f / 256.f);
            float var = q * (1.f / 256.f) - mean * mean;
            float rstd = rsqrtf(var + 1e-5f);
#pragma unroll
            for (int nt = 0; nt < 2; ++nt)
                acc[g][nt][r] = fmaxf((acc[g][nt][r] - mean) * rstd * gm[g][nt] + be[g][nt], 0.f);
        }
    }

    if (!tk.interact) {
#pragma unroll
        for (int r = 0; r < 4; ++r) {
            int grow = mt * 16 + rq * 4 + r;
#pragma unroll
            for (int nt = 0; nt < 2; ++nt) {
                int c = wave * 32 + nt * 16 + cq;
                tk.outG[(size_t)grow * 256 + c] = acc[0][nt][r];
                tk.outP[(size_t)grow * 256 + c] = acc[1][nt][r];
            }
        }
    } else {
        // per-row attention dots
#pragma unroll
        for (int r = 0; r < 4; ++r) {
#pragma unroll
            for (int g = 0; g < 2; ++g) {
                float pd = 0.f;
#pragma unroll
                for (int nt = 0; nt < 2; ++nt) pd += acc[g][nt][r] * aw[g][nt];
                pd = red16(pd);
                if (cq == 0) red_d[g][rq * 4 + r][wave] = pd;
            }
        }
        __syncthreads();
        float battP = *tk.attbP, battG = *tk.attbG;
#pragma unroll
        for (int r = 0; r < 4; ++r) {
            int row = rq * 4 + r;
            f32x4 d4 = *(const f32x4*)&red_d[0][row][0];
            f32x4 d5 = *(const f32x4*)&red_d[0][row][4];
            f32x4 e4 = *(const f32x4*)&red_d[1][row][0];
            f32x4 e5 = *(const f32x4*)&red_d[1][row][4];
            float dG = d4.x + d4.y + d4.z + d4.w + d5.x + d5.y + d5.z + d5.w;  // dot(g_align, apw)
            float dP = e4.x + e4.y + e4.z + e4.w + e5.x + e5.y + e5.z + e5.w;  // dot(p_align, agw)
            int grow = mt * 16 + row;
#pragma unroll
            for (int nt = 0; nt < 2; ++nt) {
                int c = wave * 32 + nt * 16 + cq;
                float og = acc[0][nt][r], op = acc[1][nt][r];
                tk.outG[(size_t)grow * 256 + c] =
                    op * sigm(op * dG + battP) + og * sigm(og * dP + battG);
            }
        }
    }
}

// -----------------------------------------------------------------------------
extern "C" void kernel_launch(void* const* d_in, const int* in_sizes, int n_in,
                              void* d_out, int out_size, void* d_ws, size_t ws_size,
                              hipStream_t stream) {
    const float* gfeat = (const float*)d_in[0];
    const float* pfeat = (const float*)d_in[1];
    float* out = (float*)d_out;
    const size_t S = (size_t)2048 * 256;

    float* out_common = out + 0 * S;
    float* out_syn    = out + 1 * S;
    float* out_gspec  = out + 2 * S;
    float* out_pspec  = out + 3 * S;

    u16* wf = (u16*)d_ws;                   // 6 * 65536 u16
    u16* xf = wf + 6 * 65536;               // 2 * 524288 u16
    u16* xf_g = xf;
    u16* xf_p = xf + 524288;

    PrepArgs pa;
    pa.W[0] = (const float*)d_in[2];    // gs_W
    pa.W[1] = (const float*)d_in[6];    // ps_W
    pa.W[2] = (const float*)d_in[10];   // c_g_W
    pa.W[3] = (const float*)d_in[14];   // c_p_W
    pa.W[4] = (const float*)d_in[22];   // s_g_W
    pa.W[5] = (const float*)d_in[26];   // s_p_W
    pa.xg = gfeat; pa.xp = pfeat;
    pa.wf = wf; pa.xf = xf;
    hipLaunchKernelGGL(prep_kernel, dim3(704), dim3(256), 0, stream, pa);

    FusedArgs fa;
    // pair 0: spec — G: mlp(gfeat, gs_*) -> g_spec ; P: mlp(pfeat, ps_*) -> p_spec
    fa.p[0] = { xf_g, xf_p, wf + 0 * 65536, wf + 1 * 65536,
                (const float*)d_in[3], (const float*)d_in[4], (const float*)d_in[5],
                (const float*)d_in[7], (const float*)d_in[8], (const float*)d_in[9],
                nullptr, nullptr, nullptr, nullptr,
                out_gspec, out_pspec, 0 };
    // pair 1: common — G: mlp(pfeat, c_g_*), P: mlp(gfeat, c_p_*)
    fa.p[1] = { xf_p, xf_g, wf + 2 * 65536, wf + 3 * 65536,
                (const float*)d_in[11], (const float*)d_in[12], (const float*)d_in[13],
                (const float*)d_in[15], (const float*)d_in[16], (const float*)d_in[17],
                (const float*)d_in[20] /*c_apw*/, (const float*)d_in[18] /*c_agw*/,
                (const float*)d_in[21] /*c_apb*/, (const float*)d_in[19] /*c_agb*/,
                out_common, nullptr, 1 };
    // pair 2: synergy — G: mlp(pfeat, s_g_*), P: mlp(gfeat, s_p_*)
    fa.p[2] = { xf_p, xf_g, wf + 4 * 65536, wf + 5 * 65536,
                (const float*)d_in[23], (const float*)d_in[24], (const float*)d_in[25],
                (const float*)d_in[27], (const float*)d_in[28], (const float*)d_in[29],
                (const float*)d_in[32] /*s_apw*/, (const float*)d_in[30] /*s_agw*/,
                (const float*)d_in[33] /*s_apb*/, (const float*)d_in[31] /*s_agb*/,
                out_syn, nullptr, 1 };

    hipLaunchKernelGGL(fused_kernel, dim3(384), dim3(512), 0, stream, fa);
}

// Round 8
// 23.321 us; speedup vs baseline: 2.3377x; 1.1442x over previous
//
#include <hip/hip_runtime.h>

typedef __attribute__((ext_vector_type(8))) short bf16x8;
typedef __attribute__((ext_vector_type(4))) float f32x4;
typedef unsigned short u16;
typedef unsigned int u32;

__device__ __forceinline__ u16 f2bf(float f) {
    u32 u = __builtin_bit_cast(u32, f);
    return (u16)((u + 0x7FFFu + ((u >> 16) & 1u)) >> 16);
}
__device__ __forceinline__ float sigm(float x) { return 1.f / (1.f + __expf(-x)); }
__device__ __forceinline__ float red16(float x) {
    x += __shfl_xor(x, 1, 64);
    x += __shfl_xor(x, 2, 64);
    x += __shfl_xor(x, 4, 64);
    x += __shfl_xor(x, 8, 64);
    return x;
}
__device__ __forceinline__ uint4 pack8(const float* s) {
    f32x4 v0 = *(const f32x4*)s;
    f32x4 v1 = *(const f32x4*)(s + 4);
    uint4 o;
    o.x = (u32)f2bf(v0.x) | ((u32)f2bf(v0.y) << 16);
    o.y = (u32)f2bf(v0.z) | ((u32)f2bf(v0.w) << 16);
    o.z = (u32)f2bf(v1.x) | ((u32)f2bf(v1.y) << 16);
    o.w = (u32)f2bf(v1.z) | ((u32)f2bf(v1.w) << 16);
    return o;
}

// ---------------- prep (v1, R3-exact): fp32 -> bf16 fragment order -----------
// wf layout: [mlp6][wave4][nt4][kk8][lane64][8]   (65536 u16 per mlp)
// xf layout: [tensor2][mt128][kk8][lane64][8]     (524288 u16 per tensor)
struct PrepArgs { const float* W[6]; const float* xg; const float* xp; u16* wf; u16* xf; };

__global__ __launch_bounds__(256) void prep_kernel(PrepArgs a) {
    int gid = blockIdx.x * 256 + threadIdx.x;
    if (gid < 49152) {
        int l = gid & 63, kk = (gid >> 6) & 7, nt = (gid >> 9) & 3,
            w = (gid >> 11) & 3, mlp = gid >> 13;
        int n = w * 64 + nt * 16 + (l & 15);
        int k0 = kk * 32 + (l >> 4) * 8;
        *(uint4*)(a.wf + (size_t)gid * 8) = pack8(a.W[mlp] + n * 256 + k0);
    } else if (gid < 49152 + 131072) {
        int r = gid - 49152;
        const float* x = (r >> 16) ? a.xp : a.xg;
        int q = r & 65535;
        int l = q & 63, kk = (q >> 6) & 7, mt = q >> 9;
        int row = mt * 16 + (l & 15);
        int k0 = kk * 32 + (l >> 4) * 8;
        *(uint4*)(a.xf + (size_t)r * 8) = pack8(x + row * 256 + k0);
    }
}

// ---------------- fused (R3-exact + param hoist) -----------------------------
// 384 blocks = (pair:3, mt:128). 256 thr = 4 waves; wave owns N cols
// [wave*64, wave*64+64) for BOTH gemms. No LDS/barriers in main loop.
struct PairTask {
    const u16 *xfG, *xfP;                   // A-frag tensors [128][8][64][8]
    const u16 *WG, *WP;                     // B-frag tensors [4][4][8][64][8]
    const float *bG, *gmG, *beG;
    const float *bP, *gmP, *beP;
    const float *awG, *awP;                 // awG=apw (dots oG), awP=agw (dots oP)
    const float *attbP, *attbG;             // apb, agb
    float *outG, *outP;
    int interact;
};
struct FusedArgs { PairTask p[3]; };

__global__ __launch_bounds__(256) void fused_kernel(FusedArgs args) {
    __shared__ float red_s[2][16][4];
    __shared__ float red_q[2][16][4];
    __shared__ float red_d[2][16][4];

    int wg = blockIdx.x;
    int swz = (wg & 7) * 48 + (wg >> 3);    // XCD swizzle, 384 % 8 == 0, bijective
    int pair = swz >> 7;
    int mt = swz & 127;
    PairTask tk = args.p[pair];

    int tid = threadIdx.x;
    int wave = tid >> 6;
    int lane = tid & 63;
    int cq = lane & 15, rq = lane >> 4;

    // ---- hoisted epilogue parameters: 18 independent loads, latency hides
    // under the MFMA loop below ------------------------------------------------
    float bb[2][4], gm[2][4], be[2][4], aw[2][4];
#pragma unroll
    for (int g = 0; g < 2; ++g)
#pragma unroll
        for (int nt = 0; nt < 4; ++nt) {
            int c = wave * 64 + nt * 16 + cq;
            bb[g][nt] = g ? tk.bP[c] : tk.bG[c];
            gm[g][nt] = g ? tk.gmP[c] : tk.gmG[c];
            be[g][nt] = g ? tk.beP[c] : tk.beG[c];
            aw[g][nt] = tk.interact ? (g ? tk.awP[c] : tk.awG[c]) : 0.f;
        }
    float battP = tk.interact ? *tk.attbP : 0.f;
    float battG = tk.interact ? *tk.attbG : 0.f;

    // ---- A fragments: 16 coalesced 16B/lane loads ---------------------------
    bf16x8 aF[2][8];
#pragma unroll
    for (int kk = 0; kk < 8; ++kk) {
        aF[0][kk] = *(const bf16x8*)(tk.xfG + ((size_t)(mt * 8 + kk) * 64 + lane) * 8);
        aF[1][kk] = *(const bf16x8*)(tk.xfP + ((size_t)(mt * 8 + kk) * 64 + lane) * 8);
    }

    f32x4 acc[2][4];
#pragma unroll
    for (int g = 0; g < 2; ++g)
#pragma unroll
        for (int nt = 0; nt < 4; ++nt) acc[g][nt] = (f32x4){0.f, 0.f, 0.f, 0.f};

    const u16* wb0 = tk.WG + (size_t)wave * 16384 + lane * 8;
    const u16* wb1 = tk.WP + (size_t)wave * 16384 + lane * 8;

    // ---- main loop: 64 independent B loads + 64 MFMAs, no barriers ---------
#pragma unroll
    for (int kk = 0; kk < 8; ++kk) {
#pragma unroll
        for (int nt = 0; nt < 4; ++nt) {
            bf16x8 b0 = *(const bf16x8*)(wb0 + (size_t)(nt * 8 + kk) * 512);
            acc[0][nt] = __builtin_amdgcn_mfma_f32_16x16x32_bf16(aF[0][kk], b0, acc[0][nt], 0, 0, 0);
            bf16x8 b1 = *(const bf16x8*)(wb1 + (size_t)(nt * 8 + kk) * 512);
            acc[1][nt] = __builtin_amdgcn_mfma_f32_16x16x32_bf16(aF[1][kk], b1, acc[1][nt], 0, 0, 0);
        }
    }

    // ---------------------------- epilogue ----------------------------------
    float v[2][4][4];
#pragma unroll
    for (int r = 0; r < 4; ++r) {
#pragma unroll
        for (int g = 0; g < 2; ++g) {
            float s = 0.f, q = 0.f;
#pragma unroll
            for (int nt = 0; nt < 4; ++nt) {
                float t = acc[g][nt][r] + bb[g][nt];
                v[g][nt][r] = t;
                s += t; q += t * t;
            }
            s = red16(s); q = red16(q);
            if (cq == 0) {
                red_s[g][rq * 4 + r][wave] = s;
                red_q[g][rq * 4 + r][wave] = q;
            }
        }
    }
    __syncthreads();

    float o[2][4][4];
#pragma unroll
    for (int r = 0; r < 4; ++r) {
        int row = rq * 4 + r;
#pragma unroll
        for (int g = 0; g < 2; ++g) {
            f32x4 s4 = *(const f32x4*)&red_s[g][row][0];
            f32x4 q4 = *(const f32x4*)&red_q[g][row][0];
            float s = s4.x + s4.y + s4.z + s4.w;
            float q = q4.x + q4.y + q4.z + q4.w;
            float mean = s * (1.f / 256.f);
            float var = q * (1.f / 256.f) - mean * mean;
            float rstd = rsqrtf(var + 1e-5f);
#pragma unroll
            for (int nt = 0; nt < 4; ++nt)
                o[g][nt][r] = fmaxf((v[g][nt][r] - mean) * rstd * gm[g][nt] + be[g][nt], 0.f);
        }
    }

    if (!tk.interact) {
#pragma unroll
        for (int r = 0; r < 4; ++r) {
            int grow = mt * 16 + rq * 4 + r;
#pragma unroll
            for (int nt = 0; nt < 4; ++nt) {
                int c = wave * 64 + nt * 16 + cq;
                tk.outG[(size_t)grow * 256 + c] = o[0][nt][r];
                tk.outP[(size_t)grow * 256 + c] = o[1][nt][r];
            }
        }
    } else {
#pragma unroll
        for (int r = 0; r < 4; ++r) {
            float dg = 0.f, dp = 0.f;
#pragma unroll
            for (int nt = 0; nt < 4; ++nt) {
                dg += o[0][nt][r] * aw[0][nt];
                dp += o[1][nt][r] * aw[1][nt];
            }
            dg = red16(dg); dp = red16(dp);
            if (cq == 0) {
                red_d[0][rq * 4 + r][wave] = dg;
                red_d[1][rq * 4 + r][wave] = dp;
            }
        }
        __syncthreads();
#pragma unroll
        for (int r = 0; r < 4; ++r) {
            int row = rq * 4 + r;
            f32x4 d4 = *(const f32x4*)&red_d[0][row][0];
            f32x4 e4 = *(const f32x4*)&red_d[1][row][0];
            float dG = d4.x + d4.y + d4.z + d4.w;   // dot(g_align, apw)
            float dP = e4.x + e4.y + e4.z + e4.w;   // dot(p_align, agw)
            int grow = mt * 16 + row;
#pragma unroll
            for (int nt = 0; nt < 4; ++nt) {
                int c = wave * 64 + nt * 16 + cq;
                float og = o[0][nt][r], op = o[1][nt][r];
                tk.outG[(size_t)grow * 256 + c] =
                    op * sigm(op * dG + battP) + og * sigm(og * dP + battG);
            }
        }
    }
}

// -----------------------------------------------------------------------------
extern "C" void kernel_launch(void* const* d_in, const int* in_sizes, int n_in,
                              void* d_out, int out_size, void* d_ws, size_t ws_size,
                              hipStream_t stream) {
    const float* gfeat = (const float*)d_in[0];
    const float* pfeat = (const float*)d_in[1];
    float* out = (float*)d_out;
    const size_t S = (size_t)2048 * 256;

    float* out_common = out + 0 * S;
    float* out_syn    = out + 1 * S;
    float* out_gspec  = out + 2 * S;
    float* out_pspec  = out + 3 * S;

    u16* wf = (u16*)d_ws;                   // 6 * 65536 u16
    u16* xf = wf + 6 * 65536;               // 2 * 524288 u16
    u16* xf_g = xf;
    u16* xf_p = xf + 524288;

    PrepArgs pa;
    pa.W[0] = (const float*)d_in[2];    // gs_W
    pa.W[1] = (const float*)d_in[6];    // ps_W
    pa.W[2] = (const float*)d_in[10];   // c_g_W
    pa.W[3] = (const float*)d_in[14];   // c_p_W
    pa.W[4] = (const float*)d_in[22];   // s_g_W
    pa.W[5] = (const float*)d_in[26];   // s_p_W
    pa.xg = gfeat; pa.xp = pfeat;
    pa.wf = wf; pa.xf = xf;
    hipLaunchKernelGGL(prep_kernel, dim3(704), dim3(256), 0, stream, pa);

    FusedArgs fa;
    // pair 0: spec — G: mlp(gfeat, gs_*) -> g_spec ; P: mlp(pfeat, ps_*) -> p_spec
    fa.p[0] = { xf_g, xf_p, wf + 0 * 65536, wf + 1 * 65536,
                (const float*)d_in[3], (const float*)d_in[4], (const float*)d_in[5],
                (const float*)d_in[7], (const float*)d_in[8], (const float*)d_in[9],
                nullptr, nullptr, nullptr, nullptr,
                out_gspec, out_pspec, 0 };
    // pair 1: common — G: mlp(pfeat, c_g_*), P: mlp(gfeat, c_p_*)
    fa.p[1] = { xf_p, xf_g, wf + 2 * 65536, wf + 3 * 65536,
                (const float*)d_in[11], (const float*)d_in[12], (const float*)d_in[13],
                (const float*)d_in[15], (const float*)d_in[16], (const float*)d_in[17],
                (const float*)d_in[20] /*c_apw*/, (const float*)d_in[18] /*c_agw*/,
                (const float*)d_in[21] /*c_apb*/, (const float*)d_in[19] /*c_agb*/,
                out_common, nullptr, 1 };
    // pair 2: synergy — G: mlp(pfeat, s_g_*), P: mlp(gfeat, s_p_*)
    fa.p[2] = { xf_p, xf_g, wf + 4 * 65536, wf + 5 * 65536,
                (const float*)d_in[23], (const float*)d_in[24], (const float*)d_in[25],
                (const float*)d_in[27], (const float*)d_in[28], (const float*)d_in[29],
                (const float*)d_in[32] /*s_apw*/, (const float*)d_in[30] /*s_agw*/,
                (const float*)d_in[33] /*s_apb*/, (const float*)d_in[31] /*s_agb*/,
                out_syn, nullptr, 1 };

    hipLaunchKernelGGL(fused_kernel, dim3(384), dim3(256), 0, stream, fa);
}